// Round 12
// baseline (159.680 us; speedup 1.0000x reference)
//
#include <hip/hip_runtime.h>
#include <hip/hip_bf16.h>

// PCGraphConv: iterative predictive-coding message passing.
// N_V=2000, N_SENS=784, N_E=500000, BATCH=32, T=5, lr=0.1.
// R24: counting sort ELIMINATED — W built by direct global f32 atomics.
//  R22/R23 lesson: chain cost is work-structure (3x edge reads, pk_g
//  round-trip, 1M LDS atomics), not launch gaps.
//  - k_zero4: zero dense WAcc[2000][KP] f32 (16.1MB, LLC-resident).
//  - k_init_bld: old init + ONE edge pass: atomicAdd(WAcc[d*KP+s],
//    bf16-rounded w) — 500K scattered L2-side atomics, no contention.
//  - k_conv: per dst-tile coalesced load of 16 WAcc rows -> LDS acc
//    (same layout as old k_build), then k_build's unchanged emit
//    (WAbf frags + WAdT). Addends identical to champion; only atomic
//    sum order differs (same class as LDS-atomic build).
//  - k_loop: BYTE-IDENTICAL to R21 champion loop (54-55us proven).
// Fallback: proven R4 CSR path if ws too small.

#define N_V     2000
#define N_SENS  784
#define N_INT   (N_V - N_SENS)   // 1216
#define N_E     500000
#define T_STEPS 5
#define LR_VAL  0.1f
#define NVB     (N_V * 32)       // 64000
#define NVH     (N_V * 16)       // 32000
#define KP      2016             // padded K (63 chunks of 32)
#define NCH     63               // K chunks
#define NT1     125              // dst tiles (125*16 = 2000)
#define NT2     76               // interior src tiles (76*16 = 1216)
#define FRAG_N  (2 * NCH * 64 * 8)   // 64512 u16 per A-frag table
#define NBLK    250              // edge-pass blocks
#define EPB     2000             // edges per block
#define NBLK_P  250              // persistent blocks (tile x batch-half)
#define BAR_STRIDE 32            // ints between arrival slots (128 B)
#define BAR_N   ((NBLK_P + 1) * BAR_STRIDE)
#define C_SENS  24               // chunk containing the 784 boundary
#define WACC_N  ((size_t)N_V * KP)   // 4,032,000 f32

typedef float  f32x4 __attribute__((ext_vector_type(4)));
typedef short  s16x8 __attribute__((ext_vector_type(8)));
typedef unsigned long long u64;

__device__ __forceinline__ float bits_to_f32(unsigned u) {
    union { unsigned u; float f; } c; c.u = u; return c.f;
}
__device__ __forceinline__ unsigned f32_to_bits(float f) {
    union { float f; unsigned u; } c; c.f = f; return c.u;
}
__device__ __forceinline__ unsigned short f32_to_bf16(float f) {
    unsigned u = f32_to_bits(f);
    return (unsigned short)((u + 0x7FFFu + ((u >> 16) & 1u)) >> 16);  // RNE
}
__device__ __forceinline__ float bf16_to_f32(unsigned short s) {
    return bits_to_f32((unsigned)s << 16);
}

// ---- coherent (L2-bypassing) access helpers: relaxed agent atomics ----
__device__ __forceinline__ u64 ald64(const void* p) {
    return __hip_atomic_load((const u64*)p, __ATOMIC_RELAXED,
                             __HIP_MEMORY_SCOPE_AGENT);
}
__device__ __forceinline__ void ast64(void* p, u64 v) {
    __hip_atomic_store((u64*)p, v, __ATOMIC_RELAXED, __HIP_MEMORY_SCOPE_AGENT);
}
__device__ __forceinline__ unsigned short ald16(const unsigned short* p) {
    return __hip_atomic_load(p, __ATOMIC_RELAXED, __HIP_MEMORY_SCOPE_AGENT);
}
__device__ __forceinline__ void ast16(unsigned short* p, unsigned short v) {
    __hip_atomic_store(p, v, __ATOMIC_RELAXED, __HIP_MEMORY_SCOPE_AGENT);
}
// explicit system-coherent scalar ops for the barrier words
__device__ __forceinline__ int cohld(const int* p) {
    int v;
    asm volatile("global_load_dword %0, %1, off sc0 sc1\n\ts_waitcnt vmcnt(0)"
                 : "=v"(v) : "v"(p) : "memory");
    return v;
}
__device__ __forceinline__ void cohst(int* p, int v) {
    asm volatile("global_store_dword %0, %1, off sc0 sc1"
                 :: "v"(p), "v"(v) : "memory");
}

// A-fragment u16 index for element (k, b) of fx/err tables (m = b&15).
__device__ __forceinline__ int aposKB(int k, int b) {
    int c = k >> 5, q = (k >> 3) & 3, j = k & 7;
    int h = b >> 4, m = b & 15;
    return (((h * NCH + c) * 64) + q * 16 + m) * 8 + j;
}

// ------------------------- dense/MFMA path -------------------------------

__global__ void k_zero4(uint4* a, int n4) {
    int t = blockIdx.x * blockDim.x + threadIdx.x;
    if (t < n4) { uint4 z = {0u, 0u, 0u, 0u}; a[t] = z; }
}

// merged init + dense-W atomic build (ONE edge pass).
__global__ __launch_bounds__(256) void k_init_bld(
        const int* __restrict__ src, const int* __restrict__ dst,
        const float* __restrict__ wts, const float* __restrict__ vin,
        float* __restrict__ WAcc,
        unsigned short* __restrict__ fxA, unsigned short* __restrict__ errA,
        float* __restrict__ v, float* __restrict__ out,
        unsigned short* __restrict__ WAdT, int* __restrict__ bar) {
    int b = blockIdx.x;
    int t = b * 256 + threadIdx.x;
    {   // zero pad slots k in [2000,2016) of both frag tables
        if (t < 16 * 32) {
            int k = 2000 + (t >> 5), bb = t & 31;
            fxA[aposKB(k, bb)] = 0;
            errA[aposKB(k, bb)] = 0;
        }
        // zero WAdT pad rows k in [2000,2016) for all 1216 columns
        if (t < N_INT * 2) {
            uint4 z = {0u, 0u, 0u, 0u};
            *(uint4*)(WAdT + (size_t)(t >> 1) * KP + 2000 + (t & 1) * 8) = z;
        }
        // zero barrier slots + go word
        if (t < BAR_N) bar[t] = 0;
    }
    // init: coalesced read of vin, scattered L2-hot writes
    if (t < NVB) {
        float x = vin[t];
        int bb = t / N_V;
        int i = t - bb * N_V;
        v[(i << 5) + bb] = x;
        fxA[aposKB(i, bb)] = f32_to_bf16(tanhf(x));
        if (i < N_SENS) out[t] = x;
    }
    // dense W build: one coalesced edge pass, global f32 atomics
    int base = b * EPB;
    for (int e = base + threadIdx.x; e < base + EPB; e += 256) {
        int d = dst[e], s = src[e];
        float wv = bf16_to_f32(f32_to_bf16(wts[e]));
        atomicAdd(&WAcc[(size_t)d * KP + s], wv);
    }
}

// convert dense WAcc -> WAbf fragments + TRANSPOSED WAdT.
// One block per dst tile: coalesced uint4 load of 16 rows into LDS acc
// (identical layout to old k_build's acc), then k_build's emit code.
__global__ __launch_bounds__(512) void k_conv(
        const float* __restrict__ WAcc,
        uint4* __restrict__ WAbf4, unsigned short* __restrict__ WAdT) {
    __shared__ float acc[16][KP];   // 129 KB
    int tile = blockIdx.x;
    int tid = threadIdx.x;
    {
        const uint4* gsrc = (const uint4*)(WAcc + (size_t)tile * 16 * KP);
        uint4* ldst = (uint4*)&acc[0][0];
        for (int i = tid; i < 16 * KP / 4; i += 512) ldst[i] = gsrc[i];
    }
    __syncthreads();
    // emit WAbf fragments (all 16 rows)
    for (int i = tid; i < 16 * 252; i += 512) {
        int m = i / 252, g = i - m * 252;
        int c = g >> 2, q = g & 3;
        int col = g * 8;
        unsigned short r[8];
        #pragma unroll
        for (int j = 0; j < 8; ++j) r[j] = f32_to_bf16(acc[m][col + j]);
        WAbf4[((tile * NCH + c) * 64) + q * 16 + m] = *(const uint4*)r;
    }
    // emit WAdT columns j in [784,2000): 16 bf16 (this tile's dst rows)
    for (int i = tid; i < N_INT; i += 512) {
        int j = N_SENS + i;
        unsigned short r[16];
        #pragma unroll
        for (int m = 0; m < 16; ++m) r[m] = f32_to_bf16(acc[m][j]);
        uint4* p = (uint4*)(WAdT + (size_t)i * KP + tile * 16);
        p[0] = *(const uint4*)r;
        p[1] = *(const uint4*)(r + 8);
    }
}

// Fence-free device barrier (epoch-based, monotonic). Proven R15.
__device__ __forceinline__ void gbar(int* arr, int epoch, int bx, int tid) {
    asm volatile("s_waitcnt vmcnt(0) lgkmcnt(0)" ::: "memory");
    __syncthreads();
    if (bx == 0) {
        if (tid == 0) cohst(&arr[0], epoch);
        if (tid < NBLK_P) {
            while (cohld(&arr[tid * BAR_STRIDE]) < epoch)
                __builtin_amdgcn_s_sleep(2);
        }
        __syncthreads();
        if (tid == 0) cohst(&arr[NBLK_P * BAR_STRIDE], epoch);  // go
    } else {
        if (tid == 0) {
            cohst(&arr[bx * BAR_STRIDE], epoch);
            while (cohld(&arr[NBLK_P * BAR_STRIDE]) < epoch)
                __builtin_amdgcn_s_sleep(2);
        }
        __syncthreads();
    }
}

// persistent T-loop. 250 blocks x 512 threads: tile = bx>>1, half = bx&1.
// BYTE-IDENTICAL to R21 champion. phase0: pred_const (sensory clamped);
// phase1: err (interior chunks); phase2: back + update.
__global__ __launch_bounds__(512, 1) void k_loop(
        const uint4* __restrict__ WAbf4, const unsigned short* __restrict__ WAdT,
        unsigned short* fxA, unsigned short* errA,
        float* v_cur, float* __restrict__ out, int* arr) {
    __shared__ uint4 WldsA[NCH * 64];   // 64512 B
    __shared__ uint4 WldsB[NCH * 64];   // 64512 B
    __shared__ float red[2600];         // 10400 B
    const int bx = blockIdx.x, tid = threadIdx.x;
    const int tile = bx >> 1, h = bx & 1;
    {
        const uint4* Wg = WAbf4 + (size_t)tile * (NCH * 64);
        for (int i = tid; i < NCH * 64; i += 512) WldsA[i] = Wg[i];
        if (bx < 2 * NT2) {
            for (int i = tid; i < NCH * 64; i += 512) {
                int c = i >> 6, ll = i & 63;
                int row = tile * 16 + (ll & 15);
                int k0 = c * 32 + (ll >> 4) * 8;
                WldsB[i] = *(const uint4*)(WAdT + (size_t)row * KP + k0);
            }
        }
    }
    const int w = tid >> 6, l = tid & 63;
    const int grp = l >> 4;
    float* my = &red[w * 325 + l * 5];
    int epoch = 0;
    float pc[4] = {0.f, 0.f, 0.f, 0.f};   // pred_const, valid in w==0 lanes
    __syncthreads();

    // ---------------- phase 0: pred_const (block-local, once) -----------
    {
        const int cb0 = w * 4;               // chunks cb0..cb0+3, guard <=24
        const u64* ap = (const u64*)fxA
                      + ((size_t)h * (NCH * 64) + cb0 * 64 + l) * 2;
        u64 f0[4], f1[4];
        #pragma unroll
        for (int cc = 0; cc < 4; ++cc)
            if (cb0 + cc <= C_SENS) {
                f0[cc] = ald64(ap + cc * 128);
                f1[cc] = ald64(ap + cc * 128 + 1);
                if (cb0 + cc == C_SENS && grp >= 2) { f0[cc] = 0; f1[cc] = 0; }
            }
        __builtin_amdgcn_sched_barrier(0);
        f32x4 acc = {0.f, 0.f, 0.f, 0.f};
        #pragma unroll
        for (int cc = 0; cc < 4; ++cc)
            if (cb0 + cc <= C_SENS) {
                u64 d[2] = {f0[cc], f1[cc]};
                uint4 bfrag = WldsA[(cb0 + cc) * 64 + l];
                acc = __builtin_amdgcn_mfma_f32_16x16x32_bf16(
                          *(s16x8*)d, *(s16x8*)&bfrag, acc, 0, 0, 0);
            }
        #pragma unroll
        for (int r = 0; r < 4; ++r) my[r] = acc[r];
        __syncthreads();
        if (w == 0) {
            #pragma unroll
            for (int r = 0; r < 4; ++r) {
                float sum = 0.f;
                #pragma unroll
                for (int ww = 0; ww < 8; ++ww)
                    sum += red[ww * 325 + l * 5 + r];
                pc[r] = sum;
            }
        }
        __syncthreads();   // red reused by phase 1 below
    }

    for (int t = 0; t < T_STEPS; ++t) {
        // ---------------- phase 1: err, interior chunks 24..62 ----------
        {
            const int cb = C_SENS + w * 5;   // 24,29,..,59; guard < NCH
            const u64* ap = (const u64*)fxA
                          + ((size_t)h * (NCH * 64) + cb * 64 + l) * 2;
            u64 f0[5], f1[5];
            #pragma unroll
            for (int cc = 0; cc < 5; ++cc)
                if (cb + cc < NCH) {
                    f0[cc] = ald64(ap + cc * 128);
                    f1[cc] = ald64(ap + cc * 128 + 1);
                    if (cb + cc == C_SENS && grp < 2) { f0[cc] = 0; f1[cc] = 0; }
                }
            __builtin_amdgcn_sched_barrier(0);
            f32x4 acc = {0.f, 0.f, 0.f, 0.f};
            #pragma unroll
            for (int cc = 0; cc < 5; ++cc)
                if (cb + cc < NCH) {
                    u64 d[2] = {f0[cc], f1[cc]};
                    uint4 bfrag = WldsA[(cb + cc) * 64 + l];
                    acc = __builtin_amdgcn_mfma_f32_16x16x32_bf16(
                              *(s16x8*)d, *(s16x8*)&bfrag, acc, 0, 0, 0);
                }
            #pragma unroll
            for (int r = 0; r < 4; ++r) my[r] = acc[r];
            __syncthreads();
            if (w == 0) {
                float s[4];
                #pragma unroll
                for (int r = 0; r < 4; ++r) {
                    float sum = pc[r];
                    #pragma unroll
                    for (int ww = 0; ww < 8; ++ww)
                        sum += red[ww * 325 + l * 5 + r];
                    s[r] = sum;
                }
                int i = tile * 16 + (l & 15);
                int q = l >> 4;
                int c2 = i >> 5, q2 = (i >> 3) & 3, j2 = i & 7;
                const float* vp = v_cur + (i << 5) + h * 16 + q * 4;
                union { u64 u[2]; float f[4]; } vu;
                vu.u[0] = ald64(vp);
                vu.u[1] = ald64(vp + 2);
                int base = ((h * NCH + c2) * 64 + q2 * 16) * 8 + j2;
                #pragma unroll
                for (int r = 0; r < 4; ++r)
                    ast16(&errA[base + (q * 4 + r) * 8],
                          f32_to_bf16(vu.f[r] - s[r]));
            }
        }
        ++epoch; gbar(arr, epoch, bx, tid);

        // ---------------- phase 2: back + update (bx < 152) ------------
        if (bx < 2 * NT2) {
            const int cb = w * 8;
            const u64* ap = (const u64*)errA
                          + ((size_t)h * (NCH * 64) + cb * 64 + l) * 2;
            u64 f0[8], f1[8];
            #pragma unroll
            for (int cc = 0; cc < 8; ++cc)
                if (cb + cc < NCH) {
                    f0[cc] = ald64(ap + cc * 128);
                    f1[cc] = ald64(ap + cc * 128 + 1);
                }
            __builtin_amdgcn_sched_barrier(0);
            f32x4 acc = {0.f, 0.f, 0.f, 0.f};
            #pragma unroll
            for (int cc = 0; cc < 8; ++cc)
                if (cb + cc < NCH) {
                    u64 d[2] = {f0[cc], f1[cc]};
                    uint4 bfrag = WldsB[(cb + cc) * 64 + l];
                    acc = __builtin_amdgcn_mfma_f32_16x16x32_bf16(
                              *(s16x8*)d, *(s16x8*)&bfrag, acc, 0, 0, 0);
                }
            #pragma unroll
            for (int r = 0; r < 4; ++r) my[r] = acc[r];
            __syncthreads();
            if (w == 0) {
                float s[4];
                #pragma unroll
                for (int r = 0; r < 4; ++r) {
                    float sum = 0.f;
                    #pragma unroll
                    for (int ww = 0; ww < 8; ++ww)
                        sum += red[ww * 325 + l * 5 + r];
                    s[r] = sum;
                }
                int j = N_SENS + tile * 16 + (l & 15);
                int q = l >> 4;
                int c2 = j >> 5, q2 = (j >> 3) & 3, j2 = j & 7;
                float* vp = v_cur + (j << 5) + h * 16 + q * 4;
                union { u64 u[2]; float f[4]; } vu;
                vu.u[0] = ald64(vp);
                vu.u[1] = ald64(vp + 2);
                int base = ((h * NCH + c2) * 64 + q2 * 16) * 8 + j2;
                #pragma unroll
                for (int r = 0; r < 4; ++r) {
                    float e0 = bf16_to_f32(ald16(&errA[base + (q * 4 + r) * 8]));
                    float fxv = tanhf(vu.f[r]);
                    float vn = vu.f[r] - LR_VAL * (e0 - (1.f - fxv * fxv) * s[r]);
                    vu.f[r] = vn;
                    ast16(&fxA[base + (q * 4 + r) * 8], f32_to_bf16(tanhf(vn)));
                }
                ast64(vp, vu.u[0]);
                ast64(vp + 2, vu.u[1]);
                if (t == T_STEPS - 1) {
                    #pragma unroll
                    for (int r = 0; r < 4; ++r) {
                        int b = h * 16 + q * 4 + r;
                        out[b * N_V + j] = vu.f[r];
                    }
                }
            }
        }
        if (t < T_STEPS - 1) { ++epoch; gbar(arr, epoch, bx, tid); }
    }
}

// ------------------------- fallback path (R4 CSR, proven) ----------------

__global__ void k_zero_i32(int* a, int n) {
    int t = blockIdx.x * blockDim.x + threadIdx.x;
    if (t < n) a[t] = 0;
}

__global__ void k_hist(const int* __restrict__ src, const int* __restrict__ dst,
                       int* cnt_dst, int* cnt_src) {
    int e = blockIdx.x * blockDim.x + threadIdx.x;
    if (e < N_E) {
        atomicAdd(&cnt_dst[dst[e]], 1);
        atomicAdd(&cnt_src[src[e]], 1);
    }
}

__global__ __launch_bounds__(1024) void k_scan(int* cnt_a, int* rp_a,
                                               int* cnt_b, int* rp_b) {
    __shared__ int sh[1024];
    int t = threadIdx.x;
    for (int pass = 0; pass < 2; ++pass) {
        int* cnt = pass ? cnt_b : cnt_a;
        int* rp  = pass ? rp_b  : rp_a;
        int i0 = 2 * t, i1 = 2 * t + 1;
        int c0 = (i0 < N_V) ? cnt[i0] : 0;
        int c1 = (i1 < N_V) ? cnt[i1] : 0;
        __syncthreads();
        sh[t] = c0 + c1;
        __syncthreads();
        for (int off = 1; off < 1024; off <<= 1) {
            int v = (t >= off) ? sh[t - off] : 0;
            __syncthreads();
            sh[t] += v;
            __syncthreads();
        }
        int incl = sh[t];
        int e0 = incl - (c0 + c1);
        int e1 = e0 + c0;
        if (i0 <= N_V) rp[i0] = e0;
        if (i1 <= N_V) rp[i1] = e1;
        if (i0 < N_V) cnt[i0] = e0;
        if (i1 < N_V) cnt[i1] = e1;
    }
}

__global__ void k_scatter(const int* __restrict__ src, const int* __restrict__ dst,
                          const float* __restrict__ w,
                          int* cur_dst, int* cur_src,
                          unsigned* __restrict__ pk_dst, unsigned* __restrict__ pk_src) {
    int e = blockIdx.x * blockDim.x + threadIdx.x;
    if (e < N_E) {
        int s = src[e], d = dst[e];
        unsigned wbits = (unsigned)f32_to_bf16(w[e]);
        int p = atomicAdd(&cur_dst[d], 1);
        pk_dst[p] = (wbits << 16) | (unsigned)s;
        int q = atomicAdd(&cur_src[s], 1);
        pk_src[q] = (wbits << 16) | (unsigned)d;
    }
}

__global__ void k_cast_in(const float* __restrict__ vin, float* __restrict__ v) {
    int t = blockIdx.x * blockDim.x + threadIdx.x;
    if (t < NVB) {
        int i = t >> 5, b = t & 31;
        v[t] = vin[b * N_V + i];
    }
}

__global__ void k_fx_csr(const float* __restrict__ v, unsigned short* __restrict__ fx) {
    int t = blockIdx.x * blockDim.x + threadIdx.x;
    if (t < NVB) {
        int i = t >> 5, b = t & 31;
        int h = b >> 4, b16 = b & 15;
        fx[h * NVH + i * 16 + b16] = f32_to_bf16(tanhf(v[t]));
    }
}

__global__ __launch_bounds__(256) void k_pred_err(
        const float* __restrict__ v, const unsigned short* __restrict__ fx,
        const int* __restrict__ rp, const unsigned* __restrict__ pk,
        unsigned short* __restrict__ err) {
    __shared__ unsigned short tab[NVH];
    int h  = blockIdx.x / 250;
    int vg = blockIdx.x % 250;
    {
        const uint4* g = (const uint4*)(fx + h * NVH);
        uint4* l = (uint4*)tab;
        for (int i = threadIdx.x; i < NVH / 8; i += 256) l[i] = g[i];
    }
    __syncthreads();
    int wave = threadIdx.x >> 6;
    int lane = threadIdx.x & 63;
    int b16 = lane & 15, epar = lane >> 4;
    for (int k = 0; k < 2; ++k) {
        int vid = vg * 8 + wave * 2 + k;
        int beg = rp[vid], end = rp[vid + 1];
        float sum = 0.f;
        for (int e = beg + epar; e < end; e += 4) {
            unsigned p = pk[e];
            float w = bits_to_f32(p & 0xFFFF0000u);
            int nb = (int)(p & 0xFFFFu);
            sum += w * bf16_to_f32(tab[nb * 16 + b16]);
        }
        sum += __shfl_xor(sum, 16, 64);
        sum += __shfl_xor(sum, 32, 64);
        if (epar == 0) {
            float vo = v[(vid << 5) + h * 16 + b16];
            err[h * NVH + vid * 16 + b16] = f32_to_bf16(vo - sum);
        }
    }
}

__global__ __launch_bounds__(256) void k_back_upd(
        const unsigned short* __restrict__ fx, const unsigned short* __restrict__ err,
        const int* __restrict__ rp, const unsigned* __restrict__ pk,
        float* __restrict__ v) {
    __shared__ unsigned short tab[NVH];
    int h  = blockIdx.x / 152;
    int vg = blockIdx.x % 152;
    {
        const uint4* g = (const uint4*)(err + h * NVH);
        uint4* l = (uint4*)tab;
        for (int i = threadIdx.x; i < NVH / 8; i += 256) l[i] = g[i];
    }
    __syncthreads();
    int wave = threadIdx.x >> 6;
    int lane = threadIdx.x & 63;
    int b16 = lane & 15, epar = lane >> 4;
    for (int k = 0; k < 2; ++k) {
        int vid = N_SENS + vg * 8 + wave * 2 + k;
        if (vid >= N_V) continue;
        int beg = rp[vid], end = rp[vid + 1];
        float sum = 0.f;
        for (int e = beg + epar; e < end; e += 4) {
            unsigned p = pk[e];
            float w = bits_to_f32(p & 0xFFFF0000u);
            int nb = (int)(p & 0xFFFFu);
            sum += w * bf16_to_f32(tab[nb * 16 + b16]);
        }
        sum += __shfl_xor(sum, 16, 64);
        sum += __shfl_xor(sum, 32, 64);
        if (epar == 0) {
            float e0  = bf16_to_f32(tab[vid * 16 + b16]);
            float fxv = bf16_to_f32(fx[h * NVH + vid * 16 + b16]);
            float dv = e0 - (1.f - fxv * fxv) * sum;
            v[(vid << 5) + h * 16 + b16] -= LR_VAL * dv;
        }
    }
}

__global__ void k_out_fb(const float* __restrict__ v, float* __restrict__ out) {
    int t = blockIdx.x * blockDim.x + threadIdx.x;
    if (t < NVB) {
        int b = t / N_V;
        int i = t - b * N_V;
        out[t] = v[(i << 5) + b];
    }
}

// ------------------------- host -----------------------------------------

extern "C" void kernel_launch(void* const* d_in, const int* in_sizes, int n_in,
                              void* d_out, int out_size, void* d_ws, size_t ws_size,
                              hipStream_t stream) {
    const float* vals = (const float*)d_in[0];
    const float* wts  = (const float*)d_in[1];
    const int* ei = (const int*)d_in[2];
    const int* src = ei;
    const int* dst = ei + N_E;
    float* out = (float*)d_out;

    const int EB = (N_E + 255) / 256;

    // ws layout: WAcc | WAbf | WAdT | fxA | errA | v_cur | bar  (~34.5 MB)
    const size_t WABF_T = (size_t)NT1 * NCH * 64;        // uint4 count
    const size_t WADT_N = (size_t)N_INT * KP;            // u16 count
    const size_t need = WACC_N * 4 + WABF_T * 16 + WADT_N * 2
                      + 2 * (size_t)FRAG_N * 2 + NVB * 4
                      + (size_t)BAR_N * 4 + 256;

    if (ws_size >= need) {
        float* WAcc = (float*)d_ws;
        uint4* WAbf4 = (uint4*)(WAcc + WACC_N);
        unsigned short* WAdT = (unsigned short*)(WAbf4 + WABF_T);
        unsigned short* fxA  = WAdT + WADT_N;
        unsigned short* errA = fxA + FRAG_N;
        float* v_cur = (float*)(errA + FRAG_N);
        int* bar_arr = (int*)(v_cur + NVB);    // dedicated region

        const int n4 = (int)(WACC_N / 4);      // 1,008,000 uint4
        k_zero4<<<(n4 + 255) / 256, 256, 0, stream>>>((uint4*)WAcc, n4);
        k_init_bld<<<NBLK, 256, 0, stream>>>(src, dst, wts, vals, WAcc,
                                             fxA, errA, v_cur, out, WAdT,
                                             bar_arr);
        k_conv<<<NT1, 512, 0, stream>>>(WAcc, WAbf4, WAdT);
        k_loop<<<NBLK_P, 512, 0, stream>>>(WAbf4, WAdT, fxA, errA, v_cur, out,
                                           bar_arr);
    } else {
        float* v_cur = (float*)d_ws;
        unsigned short* fx_g  = (unsigned short*)(v_cur + NVB);
        unsigned short* err_g = fx_g + NVB;
        int* rp_dst  = (int*)(err_g + NVB);
        int* rp_src  = rp_dst + 2048;
        int* cur_dst = rp_src + 2048;
        int* cur_src = cur_dst + 2048;
        unsigned* pk_dst = (unsigned*)(cur_src + 2048);
        unsigned* pk_src = pk_dst + N_E;

        k_zero_i32<<<16, 256, 0, stream>>>(cur_dst, 4096);
        k_hist<<<EB, 256, 0, stream>>>(src, dst, cur_dst, cur_src);
        k_scan<<<1, 1024, 0, stream>>>(cur_dst, rp_dst, cur_src, rp_src);
        k_scatter<<<EB, 256, 0, stream>>>(src, dst, wts, cur_dst, cur_src,
                                          pk_dst, pk_src);
        k_cast_in<<<250, 256, 0, stream>>>(vals, v_cur);
        for (int t = 0; t < T_STEPS; ++t) {
            k_fx_csr<<<250, 256, 0, stream>>>(v_cur, fx_g);
            k_pred_err<<<500, 256, 0, stream>>>(v_cur, fx_g, rp_dst, pk_dst, err_g);
            k_back_upd<<<304, 256, 0, stream>>>(fx_g, err_g, rp_src, pk_src, v_cur);
        }
        k_out_fb<<<250, 256, 0, stream>>>(v_cur, out);
    }
}

// Round 13
// 146.494 us; speedup vs baseline: 1.0900x; 1.0900x over previous
//
#include <hip/hip_runtime.h>
#include <hip/hip_bf16.h>

// PCGraphConv: iterative predictive-coding message passing.
// N_V=2000, N_SENS=784, N_E=500000, BATCH=32, T=5, lr=0.1.
// R25 = R21 (146.9us champion) with k_scan_a MERGED into k_place:
//  - k_place phase A: blocks 0..124 run k_scan_a's parallel per-tile scan
//    (identical code; sc1 stores to base_g/totals), then one gbar on a
//    SECOND barrier region (epoch-isolated from k_loop's; both zeroed by
//    k_cnt), then 125-wide LDS prefix for ts in every block, then place.
//    Placement positions bit-identical to R21.
//  - k_build/k_loop: byte-identical to R21 (loop proven 54-55us x4).
//  R22/R23/R24 post-mortems: fusion into loop (+22), serial inline scans
//  (+6), dense atomic build (+13) all regressed -> R21 chain is locally
//  optimal in work-structure; this only removes one launch+tail.
// Chain: k_cnt -> k_place(+scan) -> k_build -> k_loop.
// Fallback: proven R4 CSR path if ws too small.

#define N_V     2000
#define N_SENS  784
#define N_INT   (N_V - N_SENS)   // 1216
#define N_E     500000
#define T_STEPS 5
#define LR_VAL  0.1f
#define NVB     (N_V * 32)       // 64000
#define NVH     (N_V * 16)       // 32000
#define KP      2016             // padded K (63 chunks of 32)
#define NCH     63               // K chunks
#define NT1     125              // dst tiles (125*16 = 2000)
#define NT2     76               // interior src tiles (76*16 = 1216)
#define FRAG_N  (2 * NCH * 64 * 8)   // 64512 u16 per A-frag table
#define NBLK    250              // sort blocks
#define EPB     2000             // edges per sort block
#define NBLK_P  250              // persistent blocks (tile x batch-half)
#define BAR_STRIDE 32            // ints between arrival slots (128 B)
#define BAR_N   ((NBLK_P + 1) * BAR_STRIDE)
#define C_SENS  24               // chunk containing the 784 boundary

typedef float  f32x4 __attribute__((ext_vector_type(4)));
typedef short  s16x8 __attribute__((ext_vector_type(8)));
typedef unsigned long long u64;

__device__ __forceinline__ float bits_to_f32(unsigned u) {
    union { unsigned u; float f; } c; c.u = u; return c.f;
}
__device__ __forceinline__ unsigned f32_to_bits(float f) {
    union { float f; unsigned u; } c; c.f = f; return c.u;
}
__device__ __forceinline__ unsigned short f32_to_bf16(float f) {
    unsigned u = f32_to_bits(f);
    return (unsigned short)((u + 0x7FFFu + ((u >> 16) & 1u)) >> 16);  // RNE
}
__device__ __forceinline__ float bf16_to_f32(unsigned short s) {
    return bits_to_f32((unsigned)s << 16);
}

// ---- coherent (L2-bypassing) access helpers: relaxed agent atomics ----
__device__ __forceinline__ u64 ald64(const void* p) {
    return __hip_atomic_load((const u64*)p, __ATOMIC_RELAXED,
                             __HIP_MEMORY_SCOPE_AGENT);
}
__device__ __forceinline__ void ast64(void* p, u64 v) {
    __hip_atomic_store((u64*)p, v, __ATOMIC_RELAXED, __HIP_MEMORY_SCOPE_AGENT);
}
__device__ __forceinline__ unsigned short ald16(const unsigned short* p) {
    return __hip_atomic_load(p, __ATOMIC_RELAXED, __HIP_MEMORY_SCOPE_AGENT);
}
__device__ __forceinline__ void ast16(unsigned short* p, unsigned short v) {
    __hip_atomic_store(p, v, __ATOMIC_RELAXED, __HIP_MEMORY_SCOPE_AGENT);
}
__device__ __forceinline__ int ali32(const int* p) {
    return __hip_atomic_load(p, __ATOMIC_RELAXED, __HIP_MEMORY_SCOPE_AGENT);
}
__device__ __forceinline__ void asi32(int* p, int v) {
    __hip_atomic_store(p, v, __ATOMIC_RELAXED, __HIP_MEMORY_SCOPE_AGENT);
}
// explicit system-coherent scalar ops for the barrier words
__device__ __forceinline__ int cohld(const int* p) {
    int v;
    asm volatile("global_load_dword %0, %1, off sc0 sc1\n\ts_waitcnt vmcnt(0)"
                 : "=v"(v) : "v"(p) : "memory");
    return v;
}
__device__ __forceinline__ void cohst(int* p, int v) {
    asm volatile("global_store_dword %0, %1, off sc0 sc1"
                 :: "v"(p), "v"(v) : "memory");
}

// A-fragment u16 index for element (k, b) of fx/err tables (m = b&15).
__device__ __forceinline__ int aposKB(int k, int b) {
    int c = k >> 5, q = (k >> 3) & 3, j = k & 7;
    int h = b >> 4, m = b & 15;
    return (((h * NCH + c) * 64) + q * 16 + m) * 8 + j;
}

// ------------------------- dense/MFMA path -------------------------------

// histogram edges by dst-tile (cnt_g layout [tile][block]) + merged init:
// v_cur/fxA/out from vin; zero frag pads, WAdT pad rows, BOTH bar regions.
__global__ __launch_bounds__(256) void k_cnt(const int* __restrict__ dst,
                                             int* __restrict__ cnt_g,
                                             unsigned short* __restrict__ fxA,
                                             unsigned short* __restrict__ errA,
                                             const float* __restrict__ vin,
                                             float* __restrict__ v,
                                             float* __restrict__ out,
                                             unsigned short* __restrict__ WAdT,
                                             int* __restrict__ bar) {
    __shared__ int cnt[NT1];
    int b = blockIdx.x;
    int t = b * 256 + threadIdx.x;
    {   // zero pad slots k in [2000,2016) of both frag tables
        if (t < 16 * 32) {
            int k = 2000 + (t >> 5), bb = t & 31;
            fxA[aposKB(k, bb)] = 0;
            errA[aposKB(k, bb)] = 0;
        }
        // zero WAdT pad rows k in [2000,2016) for all 1216 columns
        if (t < N_INT * 2) {
            uint4 z = {0u, 0u, 0u, 0u};
            *(uint4*)(WAdT + (size_t)(t >> 1) * KP + 2000 + (t & 1) * 8) = z;
        }
        // zero BOTH barrier regions (k_place's and k_loop's)
        if (t < 2 * BAR_N) bar[t] = 0;
    }
    // merged k_init: coalesced read of vin, scattered L2-hot writes
    if (t < NVB) {
        float x = vin[t];
        int bb = t / N_V;
        int i = t - bb * N_V;
        v[(i << 5) + bb] = x;
        fxA[aposKB(i, bb)] = f32_to_bf16(tanhf(x));
        if (i < N_SENS) out[t] = x;
    }
    for (int i = threadIdx.x; i < NT1; i += 256) cnt[i] = 0;
    __syncthreads();
    int base = b * EPB;
    for (int e = base + threadIdx.x; e < base + EPB; e += 256)
        atomicAdd(&cnt[dst[e] >> 4], 1);
    __syncthreads();
    for (int tt = threadIdx.x; tt < NT1; tt += 256)
        cnt_g[tt * 256 + b] = cnt[tt];
}

// Fence-free device barrier (epoch-based, monotonic). Proven R15.
__device__ __forceinline__ void gbar(int* arr, int epoch, int bx, int tid) {
    asm volatile("s_waitcnt vmcnt(0) lgkmcnt(0)" ::: "memory");
    __syncthreads();
    if (bx == 0) {
        if (tid == 0) cohst(&arr[0], epoch);
        if (tid < NBLK_P) {
            while (cohld(&arr[tid * BAR_STRIDE]) < epoch)
                __builtin_amdgcn_s_sleep(2);
        }
        __syncthreads();
        if (tid == 0) cohst(&arr[NBLK_P * BAR_STRIDE], epoch);  // go
    } else {
        if (tid == 0) {
            cohst(&arr[bx * BAR_STRIDE], epoch);
            while (cohld(&arr[NBLK_P * BAR_STRIDE]) < epoch)
                __builtin_amdgcn_s_sleep(2);
        }
        __syncthreads();
    }
}

// scan (phase A, blocks 0..124 = k_scan_a body) + gbar + place.
// Placement positions bit-identical to R21's k_scan_a + k_place.
__global__ __launch_bounds__(256) void k_place(
        const int* __restrict__ src, const int* __restrict__ dst,
        const float* __restrict__ w, const int* __restrict__ cnt_g,
        int* __restrict__ base_g, int* __restrict__ totals,
        unsigned* __restrict__ pk_g, int* __restrict__ bar2) {
    __shared__ int sh[256];
    __shared__ int ts[NT1];
    __shared__ int cur[NT1];
    int b = blockIdx.x, tid = threadIdx.x;
    // ---- phase A: per-tile exclusive scan over blocks (tile = b) ----
    if (b < NT1) {
        int v = (tid < NBLK) ? cnt_g[b * 256 + tid] : 0;
        sh[tid] = v;
        __syncthreads();
        for (int off = 1; off < 256; off <<= 1) {
            int x = (tid >= off) ? sh[tid - off] : 0;
            __syncthreads();
            sh[tid] += x;
            __syncthreads();
        }
        if (tid < NBLK) asi32(&base_g[b * 256 + tid], sh[tid] - v);
        if (tid == 255) asi32(&totals[b], sh[255]);
    }
    gbar(bar2, 1, b, tid);
    // ---- phase B: ts = exclusive scan of totals (LDS, every block) ----
    {
        int tv = (tid < NT1) ? ali32(&totals[tid]) : 0;
        if (tid < 128) sh[tid] = tv;
        __syncthreads();
        for (int off = 1; off < 128; off <<= 1) {
            int x = (tid >= off && tid < 128) ? sh[tid - off] : 0;
            __syncthreads();
            if (tid < 128) sh[tid] += x;
            __syncthreads();
        }
        if (tid < NT1) ts[tid] = sh[tid] - tv;   // exclusive
    }
    __syncthreads();
    if (tid < NT1) cur[tid] = ts[tid] + ali32(&base_g[tid * 256 + b]);
    __syncthreads();
    // ---- phase C: place ----
    int base = b * EPB;
    for (int e = base + tid; e < base + EPB; e += 256) {
        int d = dst[e];
        unsigned pk = ((unsigned)f32_to_bf16(w[e]) << 16)
                    | ((unsigned)(d & 15) << 11) | (unsigned)src[e];
        int p = atomicAdd(&cur[d >> 4], 1);
        pk_g[p] = pk;
    }
}

// build WAbf fragments + TRANSPOSED dense bf16 WAdT from sorted edges.
// One block per tile, 512 threads: acc[16][KP] = 129 KB LDS.
__global__ __launch_bounds__(512) void k_build(
        const unsigned* __restrict__ pk_g, const int* __restrict__ totals,
        uint4* __restrict__ WAbf4, unsigned short* __restrict__ WAdT) {
    __shared__ float acc[16][KP];   // 129 KB
    __shared__ int ts[NT1 + 1];
    int tile = blockIdx.x;
    for (int i = threadIdx.x; i < 16 * KP / 4; i += 512)
        ((float4*)&acc[0][0])[i] = make_float4(0.f, 0.f, 0.f, 0.f);
    if (threadIdx.x == 0) {
        int a = 0;
        for (int t = 0; t < NT1; ++t) { ts[t] = a; a += totals[t]; }
        ts[NT1] = a;
    }
    __syncthreads();
    int beg = ts[tile], end = ts[tile + 1];
    for (int e = beg + threadIdx.x; e < end; e += 512) {
        unsigned pk = pk_g[e];
        int row = (int)((pk >> 11) & 15u);
        atomicAdd(&acc[row][pk & 0x7FFu], bf16_to_f32((unsigned short)(pk >> 16)));
    }
    __syncthreads();
    // emit WAbf fragments (all 16 rows)
    for (int i = threadIdx.x; i < 16 * 252; i += 512) {
        int m = i / 252, g = i - m * 252;
        int c = g >> 2, q = g & 3;
        int col = g * 8;
        unsigned short r[8];
        #pragma unroll
        for (int j = 0; j < 8; ++j) r[j] = f32_to_bf16(acc[m][col + j]);
        WAbf4[((tile * NCH + c) * 64) + q * 16 + m] = *(const uint4*)r;
    }
    // emit WAdT columns j in [784,2000): 16 bf16 (this tile's dst rows)
    for (int i = threadIdx.x; i < N_INT; i += 512) {
        int j = N_SENS + i;
        unsigned short r[16];
        #pragma unroll
        for (int m = 0; m < 16; ++m) r[m] = f32_to_bf16(acc[m][j]);
        uint4* p = (uint4*)(WAdT + (size_t)i * KP + tile * 16);
        p[0] = *(const uint4*)r;
        p[1] = *(const uint4*)(r + 8);
    }
}

// persistent T-loop. 250 blocks x 512 threads: tile = bx>>1, half = bx&1.
// BYTE-IDENTICAL to R21 champion. phase0: pred_const (sensory clamped);
// phase1: err (interior chunks 24..62); phase2: back + update.
__global__ __launch_bounds__(512, 1) void k_loop(
        const uint4* __restrict__ WAbf4, const unsigned short* __restrict__ WAdT,
        unsigned short* fxA, unsigned short* errA,
        float* v_cur, float* __restrict__ out, int* arr) {
    __shared__ uint4 WldsA[NCH * 64];   // 64512 B
    __shared__ uint4 WldsB[NCH * 64];   // 64512 B
    __shared__ float red[2600];         // 10400 B
    const int bx = blockIdx.x, tid = threadIdx.x;
    const int tile = bx >> 1, h = bx & 1;
    {
        const uint4* Wg = WAbf4 + (size_t)tile * (NCH * 64);
        for (int i = tid; i < NCH * 64; i += 512) WldsA[i] = Wg[i];
        if (bx < 2 * NT2) {
            for (int i = tid; i < NCH * 64; i += 512) {
                int c = i >> 6, ll = i & 63;
                int row = tile * 16 + (ll & 15);
                int k0 = c * 32 + (ll >> 4) * 8;
                WldsB[i] = *(const uint4*)(WAdT + (size_t)row * KP + k0);
            }
        }
    }
    const int w = tid >> 6, l = tid & 63;
    const int grp = l >> 4;
    float* my = &red[w * 325 + l * 5];
    int epoch = 0;
    float pc[4] = {0.f, 0.f, 0.f, 0.f};   // pred_const, valid in w==0 lanes
    __syncthreads();

    // ---------------- phase 0: pred_const (block-local, once) -----------
    {
        const int cb0 = w * 4;               // chunks cb0..cb0+3, guard <=24
        const u64* ap = (const u64*)fxA
                      + ((size_t)h * (NCH * 64) + cb0 * 64 + l) * 2;
        u64 f0[4], f1[4];
        #pragma unroll
        for (int cc = 0; cc < 4; ++cc)
            if (cb0 + cc <= C_SENS) {
                f0[cc] = ald64(ap + cc * 128);
                f1[cc] = ald64(ap + cc * 128 + 1);
                if (cb0 + cc == C_SENS && grp >= 2) { f0[cc] = 0; f1[cc] = 0; }
            }
        __builtin_amdgcn_sched_barrier(0);
        f32x4 acc = {0.f, 0.f, 0.f, 0.f};
        #pragma unroll
        for (int cc = 0; cc < 4; ++cc)
            if (cb0 + cc <= C_SENS) {
                u64 d[2] = {f0[cc], f1[cc]};
                uint4 bfrag = WldsA[(cb0 + cc) * 64 + l];
                acc = __builtin_amdgcn_mfma_f32_16x16x32_bf16(
                          *(s16x8*)d, *(s16x8*)&bfrag, acc, 0, 0, 0);
            }
        #pragma unroll
        for (int r = 0; r < 4; ++r) my[r] = acc[r];
        __syncthreads();
        if (w == 0) {
            #pragma unroll
            for (int r = 0; r < 4; ++r) {
                float sum = 0.f;
                #pragma unroll
                for (int ww = 0; ww < 8; ++ww)
                    sum += red[ww * 325 + l * 5 + r];
                pc[r] = sum;
            }
        }
        __syncthreads();   // red reused by phase 1 below
    }

    for (int t = 0; t < T_STEPS; ++t) {
        // ---------------- phase 1: err, interior chunks 24..62 ----------
        {
            const int cb = C_SENS + w * 5;   // 24,29,..,59; guard < NCH
            const u64* ap = (const u64*)fxA
                          + ((size_t)h * (NCH * 64) + cb * 64 + l) * 2;
            u64 f0[5], f1[5];
            #pragma unroll
            for (int cc = 0; cc < 5; ++cc)
                if (cb + cc < NCH) {
                    f0[cc] = ald64(ap + cc * 128);
                    f1[cc] = ald64(ap + cc * 128 + 1);
                    if (cb + cc == C_SENS && grp < 2) { f0[cc] = 0; f1[cc] = 0; }
                }
            __builtin_amdgcn_sched_barrier(0);
            f32x4 acc = {0.f, 0.f, 0.f, 0.f};
            #pragma unroll
            for (int cc = 0; cc < 5; ++cc)
                if (cb + cc < NCH) {
                    u64 d[2] = {f0[cc], f1[cc]};
                    uint4 bfrag = WldsA[(cb + cc) * 64 + l];
                    acc = __builtin_amdgcn_mfma_f32_16x16x32_bf16(
                              *(s16x8*)d, *(s16x8*)&bfrag, acc, 0, 0, 0);
                }
            #pragma unroll
            for (int r = 0; r < 4; ++r) my[r] = acc[r];
            __syncthreads();
            if (w == 0) {
                float s[4];
                #pragma unroll
                for (int r = 0; r < 4; ++r) {
                    float sum = pc[r];
                    #pragma unroll
                    for (int ww = 0; ww < 8; ++ww)
                        sum += red[ww * 325 + l * 5 + r];
                    s[r] = sum;
                }
                int i = tile * 16 + (l & 15);
                int q = l >> 4;
                int c2 = i >> 5, q2 = (i >> 3) & 3, j2 = i & 7;
                const float* vp = v_cur + (i << 5) + h * 16 + q * 4;
                union { u64 u[2]; float f[4]; } vu;
                vu.u[0] = ald64(vp);
                vu.u[1] = ald64(vp + 2);
                int base = ((h * NCH + c2) * 64 + q2 * 16) * 8 + j2;
                #pragma unroll
                for (int r = 0; r < 4; ++r)
                    ast16(&errA[base + (q * 4 + r) * 8],
                          f32_to_bf16(vu.f[r] - s[r]));
            }
        }
        ++epoch; gbar(arr, epoch, bx, tid);

        // ---------------- phase 2: back + update (bx < 152) ------------
        if (bx < 2 * NT2) {
            const int cb = w * 8;
            const u64* ap = (const u64*)errA
                          + ((size_t)h * (NCH * 64) + cb * 64 + l) * 2;
            u64 f0[8], f1[8];
            #pragma unroll
            for (int cc = 0; cc < 8; ++cc)
                if (cb + cc < NCH) {
                    f0[cc] = ald64(ap + cc * 128);
                    f1[cc] = ald64(ap + cc * 128 + 1);
                }
            __builtin_amdgcn_sched_barrier(0);
            f32x4 acc = {0.f, 0.f, 0.f, 0.f};
            #pragma unroll
            for (int cc = 0; cc < 8; ++cc)
                if (cb + cc < NCH) {
                    u64 d[2] = {f0[cc], f1[cc]};
                    uint4 bfrag = WldsB[(cb + cc) * 64 + l];
                    acc = __builtin_amdgcn_mfma_f32_16x16x32_bf16(
                              *(s16x8*)d, *(s16x8*)&bfrag, acc, 0, 0, 0);
                }
            #pragma unroll
            for (int r = 0; r < 4; ++r) my[r] = acc[r];
            __syncthreads();
            if (w == 0) {
                float s[4];
                #pragma unroll
                for (int r = 0; r < 4; ++r) {
                    float sum = 0.f;
                    #pragma unroll
                    for (int ww = 0; ww < 8; ++ww)
                        sum += red[ww * 325 + l * 5 + r];
                    s[r] = sum;
                }
                int j = N_SENS + tile * 16 + (l & 15);
                int q = l >> 4;
                int c2 = j >> 5, q2 = (j >> 3) & 3, j2 = j & 7;
                float* vp = v_cur + (j << 5) + h * 16 + q * 4;
                union { u64 u[2]; float f[4]; } vu;
                vu.u[0] = ald64(vp);
                vu.u[1] = ald64(vp + 2);
                int base = ((h * NCH + c2) * 64 + q2 * 16) * 8 + j2;
                #pragma unroll
                for (int r = 0; r < 4; ++r) {
                    float e0 = bf16_to_f32(ald16(&errA[base + (q * 4 + r) * 8]));
                    float fxv = tanhf(vu.f[r]);
                    float vn = vu.f[r] - LR_VAL * (e0 - (1.f - fxv * fxv) * s[r]);
                    vu.f[r] = vn;
                    ast16(&fxA[base + (q * 4 + r) * 8], f32_to_bf16(tanhf(vn)));
                }
                ast64(vp, vu.u[0]);
                ast64(vp + 2, vu.u[1]);
                if (t == T_STEPS - 1) {
                    #pragma unroll
                    for (int r = 0; r < 4; ++r) {
                        int b = h * 16 + q * 4 + r;
                        out[b * N_V + j] = vu.f[r];
                    }
                }
            }
        }
        if (t < T_STEPS - 1) { ++epoch; gbar(arr, epoch, bx, tid); }
    }
}

// ------------------------- fallback path (R4 CSR, proven) ----------------

__global__ void k_zero_i32(int* a, int n) {
    int t = blockIdx.x * blockDim.x + threadIdx.x;
    if (t < n) a[t] = 0;
}

__global__ void k_hist(const int* __restrict__ src, const int* __restrict__ dst,
                       int* cnt_dst, int* cnt_src) {
    int e = blockIdx.x * blockDim.x + threadIdx.x;
    if (e < N_E) {
        atomicAdd(&cnt_dst[dst[e]], 1);
        atomicAdd(&cnt_src[src[e]], 1);
    }
}

__global__ __launch_bounds__(1024) void k_scan(int* cnt_a, int* rp_a,
                                               int* cnt_b, int* rp_b) {
    __shared__ int sh[1024];
    int t = threadIdx.x;
    for (int pass = 0; pass < 2; ++pass) {
        int* cnt = pass ? cnt_b : cnt_a;
        int* rp  = pass ? rp_b  : rp_a;
        int i0 = 2 * t, i1 = 2 * t + 1;
        int c0 = (i0 < N_V) ? cnt[i0] : 0;
        int c1 = (i1 < N_V) ? cnt[i1] : 0;
        __syncthreads();
        sh[t] = c0 + c1;
        __syncthreads();
        for (int off = 1; off < 1024; off <<= 1) {
            int v = (t >= off) ? sh[t - off] : 0;
            __syncthreads();
            sh[t] += v;
            __syncthreads();
        }
        int incl = sh[t];
        int e0 = incl - (c0 + c1);
        int e1 = e0 + c0;
        if (i0 <= N_V) rp[i0] = e0;
        if (i1 <= N_V) rp[i1] = e1;
        if (i0 < N_V) cnt[i0] = e0;
        if (i1 < N_V) cnt[i1] = e1;
    }
}

__global__ void k_scatter(const int* __restrict__ src, const int* __restrict__ dst,
                          const float* __restrict__ w,
                          int* cur_dst, int* cur_src,
                          unsigned* __restrict__ pk_dst, unsigned* __restrict__ pk_src) {
    int e = blockIdx.x * blockDim.x + threadIdx.x;
    if (e < N_E) {
        int s = src[e], d = dst[e];
        unsigned wbits = (unsigned)f32_to_bf16(w[e]);
        int p = atomicAdd(&cur_dst[d], 1);
        pk_dst[p] = (wbits << 16) | (unsigned)s;
        int q = atomicAdd(&cur_src[s], 1);
        pk_src[q] = (wbits << 16) | (unsigned)d;
    }
}

__global__ void k_cast_in(const float* __restrict__ vin, float* __restrict__ v) {
    int t = blockIdx.x * blockDim.x + threadIdx.x;
    if (t < NVB) {
        int i = t >> 5, b = t & 31;
        v[t] = vin[b * N_V + i];
    }
}

__global__ void k_fx_csr(const float* __restrict__ v, unsigned short* __restrict__ fx) {
    int t = blockIdx.x * blockDim.x + threadIdx.x;
    if (t < NVB) {
        int i = t >> 5, b = t & 31;
        int h = b >> 4, b16 = b & 15;
        fx[h * NVH + i * 16 + b16] = f32_to_bf16(tanhf(v[t]));
    }
}

__global__ __launch_bounds__(256) void k_pred_err(
        const float* __restrict__ v, const unsigned short* __restrict__ fx,
        const int* __restrict__ rp, const unsigned* __restrict__ pk,
        unsigned short* __restrict__ err) {
    __shared__ unsigned short tab[NVH];
    int h  = blockIdx.x / 250;
    int vg = blockIdx.x % 250;
    {
        const uint4* g = (const uint4*)(fx + h * NVH);
        uint4* l = (uint4*)tab;
        for (int i = threadIdx.x; i < NVH / 8; i += 256) l[i] = g[i];
    }
    __syncthreads();
    int wave = threadIdx.x >> 6;
    int lane = threadIdx.x & 63;
    int b16 = lane & 15, epar = lane >> 4;
    for (int k = 0; k < 2; ++k) {
        int vid = vg * 8 + wave * 2 + k;
        int beg = rp[vid], end = rp[vid + 1];
        float sum = 0.f;
        for (int e = beg + epar; e < end; e += 4) {
            unsigned p = pk[e];
            float w = bits_to_f32(p & 0xFFFF0000u);
            int nb = (int)(p & 0xFFFFu);
            sum += w * bf16_to_f32(tab[nb * 16 + b16]);
        }
        sum += __shfl_xor(sum, 16, 64);
        sum += __shfl_xor(sum, 32, 64);
        if (epar == 0) {
            float vo = v[(vid << 5) + h * 16 + b16];
            err[h * NVH + vid * 16 + b16] = f32_to_bf16(vo - sum);
        }
    }
}

__global__ __launch_bounds__(256) void k_back_upd(
        const unsigned short* __restrict__ fx, const unsigned short* __restrict__ err,
        const int* __restrict__ rp, const unsigned* __restrict__ pk,
        float* __restrict__ v) {
    __shared__ unsigned short tab[NVH];
    int h  = blockIdx.x / 152;
    int vg = blockIdx.x % 152;
    {
        const uint4* g = (const uint4*)(err + h * NVH);
        uint4* l = (uint4*)tab;
        for (int i = threadIdx.x; i < NVH / 8; i += 256) l[i] = g[i];
    }
    __syncthreads();
    int wave = threadIdx.x >> 6;
    int lane = threadIdx.x & 63;
    int b16 = lane & 15, epar = lane >> 4;
    for (int k = 0; k < 2; ++k) {
        int vid = N_SENS + vg * 8 + wave * 2 + k;
        if (vid >= N_V) continue;
        int beg = rp[vid], end = rp[vid + 1];
        float sum = 0.f;
        for (int e = beg + epar; e < end; e += 4) {
            unsigned p = pk[e];
            float w = bits_to_f32(p & 0xFFFF0000u);
            int nb = (int)(p & 0xFFFFu);
            sum += w * bf16_to_f32(tab[nb * 16 + b16]);
        }
        sum += __shfl_xor(sum, 16, 64);
        sum += __shfl_xor(sum, 32, 64);
        if (epar == 0) {
            float e0  = bf16_to_f32(tab[vid * 16 + b16]);
            float fxv = bf16_to_f32(fx[h * NVH + vid * 16 + b16]);
            float dv = e0 - (1.f - fxv * fxv) * sum;
            v[(vid << 5) + h * 16 + b16] -= LR_VAL * dv;
        }
    }
}

__global__ void k_out_fb(const float* __restrict__ v, float* __restrict__ out) {
    int t = blockIdx.x * blockDim.x + threadIdx.x;
    if (t < NVB) {
        int b = t / N_V;
        int i = t - b * N_V;
        out[t] = v[(i << 5) + b];
    }
}

// ------------------------- host -----------------------------------------

extern "C" void kernel_launch(void* const* d_in, const int* in_sizes, int n_in,
                              void* d_out, int out_size, void* d_ws, size_t ws_size,
                              hipStream_t stream) {
    const float* vals = (const float*)d_in[0];
    const float* wts  = (const float*)d_in[1];
    const int* ei = (const int*)d_in[2];
    const int* src = ei;
    const int* dst = ei + N_E;
    float* out = (float*)d_out;

    const int EB = (N_E + 255) / 256;

    // ws layout: pk_g | cnt_g | base_g | totals | WAdT | WAbf | fxA | errA
    //            | v_cur | bar(x2)   (~20.6 MB)
    const size_t WABF_T = (size_t)NT1 * NCH * 64;        // uint4 count
    const size_t WADT_N = (size_t)N_INT * KP;            // u16 count
    const size_t need = (size_t)N_E * 4 + 2 * NT1 * 256 * 4 + 512
                      + WADT_N * 2 + WABF_T * 16
                      + 2 * (size_t)FRAG_N * 2 + NVB * 4
                      + 2 * (size_t)BAR_N * 4 + 256;

    if (ws_size >= need) {
        unsigned* pk_g = (unsigned*)d_ws;
        int* cnt_g  = (int*)(pk_g + N_E);
        int* base_g = cnt_g + NT1 * 256;
        int* totals = base_g + NT1 * 256;
        unsigned short* WAdT = (unsigned short*)(totals + 128);
        uint4* WAbf4 = (uint4*)(WAdT + WADT_N);
        unsigned short* fxA  = (unsigned short*)(WAbf4 + WABF_T);
        unsigned short* errA = fxA + FRAG_N;
        float* v_cur = (float*)(errA + FRAG_N);
        int* bar_arr = (int*)(v_cur + NVB);    // k_loop's region
        int* bar2    = bar_arr + BAR_N;        // k_place's region

        k_cnt<<<NBLK, 256, 0, stream>>>(dst, cnt_g, fxA, errA, vals, v_cur,
                                        out, WAdT, bar_arr);
        k_place<<<NBLK, 256, 0, stream>>>(src, dst, wts, cnt_g, base_g,
                                          totals, pk_g, bar2);
        k_build<<<NT1, 512, 0, stream>>>(pk_g, totals, WAbf4, WAdT);
        k_loop<<<NBLK_P, 512, 0, stream>>>(WAbf4, WAdT, fxA, errA, v_cur, out,
                                           bar_arr);
    } else {
        float* v_cur = (float*)d_ws;
        unsigned short* fx_g  = (unsigned short*)(v_cur + NVB);
        unsigned short* err_g = fx_g + NVB;
        int* rp_dst  = (int*)(err_g + NVB);
        int* rp_src  = rp_dst + 2048;
        int* cur_dst = rp_src + 2048;
        int* cur_src = cur_dst + 2048;
        unsigned* pk_dst = (unsigned*)(cur_src + 2048);
        unsigned* pk_src = pk_dst + N_E;

        k_zero_i32<<<16, 256, 0, stream>>>(cur_dst, 4096);
        k_hist<<<EB, 256, 0, stream>>>(src, dst, cur_dst, cur_src);
        k_scan<<<1, 1024, 0, stream>>>(cur_dst, rp_dst, cur_src, rp_src);
        k_scatter<<<EB, 256, 0, stream>>>(src, dst, wts, cur_dst, cur_src,
                                          pk_dst, pk_src);
        k_cast_in<<<250, 256, 0, stream>>>(vals, v_cur);
        for (int t = 0; t < T_STEPS; ++t) {
            k_fx_csr<<<250, 256, 0, stream>>>(v_cur, fx_g);
            k_pred_err<<<500, 256, 0, stream>>>(v_cur, fx_g, rp_dst, pk_dst, err_g);
            k_back_upd<<<304, 256, 0, stream>>>(fx_g, err_g, rp_src, pk_src, v_cur);
        }
        k_out_fb<<<250, 256, 0, stream>>>(v_cur, out);
    }
}